// Round 4
// baseline (549.956 us; speedup 1.0000x reference)
//
#include <hip/hip_runtime.h>

#define NNODES 50000
#define NEDGES 800000
#define NFEAT 512
#define NHID 64
#define NCLASSES 40
#define NLAYERS 10
#define ALPHA 0.8f

// ---------------- CSR build (once per call) ----------------

__global__ void zero_counts_kernel(int* __restrict__ counts) {
    int i = blockIdx.x * blockDim.x + threadIdx.x;
    if (i < NNODES) counts[i] = 0;
}

__global__ void hist_kernel(const int* __restrict__ dst, int* __restrict__ counts) {
    int e = blockIdx.x * blockDim.x + threadIdx.x;
    if (e >= NEDGES) return;
    atomicAdd(&counts[dst[e]], 1);
}

__global__ void scan1_kernel(const int* __restrict__ counts,
                             int* __restrict__ row_ptr,
                             int* __restrict__ bsum) {
    __shared__ int sd[1024];
    int tid = threadIdx.x;
    int i = blockIdx.x * 1024 + tid;
    int v = (i < NNODES) ? counts[i] : 0;
    sd[tid] = v;
    __syncthreads();
    for (int off = 1; off < 1024; off <<= 1) {
        int t = (tid >= off) ? sd[tid - off] : 0;
        __syncthreads();
        sd[tid] += t;
        __syncthreads();
    }
    if (i < NNODES) row_ptr[i] = sd[tid] - v;
    if (tid == 1023) bsum[blockIdx.x] = sd[1023];
}

__global__ void scan2_kernel(const int* __restrict__ bsum, int* __restrict__ boff) {
    int tid = threadIdx.x;
    const int NB = (NNODES + 1023) / 1024;   // 49
    int v0 = (tid < NB) ? bsum[tid] : 0;
    int v = v0;
#pragma unroll
    for (int off = 1; off < 64; off <<= 1) {
        int t = __shfl_up(v, off);
        if (tid >= off) v += t;
    }
    if (tid < NB) boff[tid] = v - v0;
    if (tid == NB - 1) boff[NB] = v;
}

__global__ void scan3_kernel(const int* __restrict__ boff,
                             int* __restrict__ row_ptr,
                             int* __restrict__ cursor) {
    int i = blockIdx.x * blockDim.x + threadIdx.x;
    if (i < NNODES) {
        int rp = row_ptr[i] + boff[i >> 10];
        row_ptr[i] = rp;
        cursor[i] = rp;
    } else if (i == NNODES) {
        row_ptr[NNODES] = boff[(NNODES + 1023) / 1024];
    }
}

__global__ void csr_scatter_kernel(const int* __restrict__ src,
                                   const int* __restrict__ dst,
                                   const float* __restrict__ ew,
                                   int* __restrict__ cursor,
                                   int2* __restrict__ edata) {
    int e = blockIdx.x * blockDim.x + threadIdx.x;
    if (e >= NEDGES) return;
    int d = dst[e];
    int pos = atomicAdd(&cursor[d], 1);
    int2 ed;
    ed.x = src[e];
    ed.y = __float_as_int(ALPHA * ew[e]);
    edata[pos] = ed;
}

// ---------------- dense kernels ----------------

// h = x @ W_in + b_in. BM=64 nodes, BN=64 cols, BK=32; 256 threads.
// Thread tile: 2 nodes x 8 cols. x staged transposed in LDS; W float4
// broadcast from L1 (8 KB tile, hot).
#define LIN_KC 32
__global__ __launch_bounds__(256) void linear_in_kernel(
        const float* __restrict__ x, const float* __restrict__ W,
        const float* __restrict__ b, float* __restrict__ h) {
    __shared__ float xs[LIN_KC][68];    // pad 64->68: stores 2-way (free), reads conflict-free
    int tid = threadIdx.x;
    int nb = blockIdx.x * 64;
    int cg = tid & 7;                   // col group: cols cg*8..cg*8+7
    int ng = tid >> 3;                  // node group: nodes ng*2, ng*2+1
    int jb = cg * 8;
    float acc[2][8];
#pragma unroll
    for (int i = 0; i < 2; ++i)
#pragma unroll
        for (int c = 0; c < 8; ++c) acc[i][c] = 0.f;

    for (int kc = 0; kc < NFEAT; kc += LIN_KC) {
        // stage x[nb..nb+63][kc..kc+31] transposed: 512 float4, 2 per thread
#pragma unroll
        for (int q = 0; q < 2; ++q) {
            int li = tid + q * 256;     // 0..511
            int r = li & 63;            // node 0..63
            int f4 = li >> 6;           // k-quad 0..7
            int row = nb + r;
            float4 v = make_float4(0.f, 0.f, 0.f, 0.f);
            if (row < NNODES)
                v = *(const float4*)(x + (size_t)row * NFEAT + kc + f4 * 4);
            xs[f4 * 4 + 0][r] = v.x;
            xs[f4 * 4 + 1][r] = v.y;
            xs[f4 * 4 + 2][r] = v.z;
            xs[f4 * 4 + 3][r] = v.w;
        }
        __syncthreads();
#pragma unroll 8
        for (int k = 0; k < LIN_KC; ++k) {
            float2 a = *(const float2*)(&xs[k][ng * 2]);
            const float* wr = W + (size_t)(kc + k) * NHID + jb;
            float4 w0 = *(const float4*)(wr);
            float4 w1 = *(const float4*)(wr + 4);
            float wv[8];
            *(float4*)(wv) = w0; *(float4*)(wv + 4) = w1;
#pragma unroll
            for (int c = 0; c < 8; ++c) {
                acc[0][c] = fmaf(a.x, wv[c], acc[0][c]);
                acc[1][c] = fmaf(a.y, wv[c], acc[1][c]);
            }
        }
        __syncthreads();
    }
    float4 b0 = *(const float4*)(b + jb);
    float4 b1 = *(const float4*)(b + jb + 4);
#pragma unroll
    for (int i = 0; i < 2; ++i) {
        int n = nb + ng * 2 + i;
        if (n < NNODES) {
            float4 o0, o1;
            o0.x = acc[i][0] + b0.x; o0.y = acc[i][1] + b0.y;
            o0.z = acc[i][2] + b0.z; o0.w = acc[i][3] + b0.w;
            o1.x = acc[i][4] + b1.x; o1.y = acc[i][5] + b1.y;
            o1.z = acc[i][6] + b1.z; o1.w = acc[i][7] + b1.w;
            float* hp = h + (size_t)n * NHID + jb;
            *(float4*)(hp) = o0;
            *(float4*)(hp + 4) = o1;
        }
    }
}

// pull SpMM: 4 nodes/wave, 16 lanes x float4 per node, 4 edges in flight.
__global__ __launch_bounds__(256) void spmm_pull_kernel(
        const int2* __restrict__ edata, const int* __restrict__ row_ptr,
        const float* __restrict__ h_cur, const float* __restrict__ h0,
        float* __restrict__ h_next) {
    int gid = blockIdx.x * blockDim.x + threadIdx.x;
    int wave = gid >> 6;
    int lane = threadIdx.x & 63;
    int grp = lane >> 4;
    int fl = (lane & 15) << 2;
    int node = wave * 4 + grp;          // NNODES % 4 == 0
    int beg = row_ptr[node];
    int deg = row_ptr[node + 1] - beg;
    int steps = deg;
    steps = max(steps, __shfl_xor(steps, 16));
    steps = max(steps, __shfl_xor(steps, 32));

    float4 acc = make_float4(0.f, 0.f, 0.f, 0.f);
    int t = 0;
    for (; t + 3 < steps; t += 4) {
#pragma unroll
        for (int u = 0; u < 4; ++u) {
            // issue all 4 edata loads + gathers before consuming (compiler
            // schedules the independent loads back-to-back)
        }
        bool v0 = (t < deg), v1 = (t + 1 < deg), v2 = (t + 2 < deg), v3 = (t + 3 < deg);
        int2 e0 = edata[v0 ? (beg + t) : 0];
        int2 e1 = edata[v1 ? (beg + t + 1) : 0];
        int2 e2 = edata[v2 ? (beg + t + 2) : 0];
        int2 e3 = edata[v3 ? (beg + t + 3) : 0];
        float w0 = v0 ? __int_as_float(e0.y) : 0.f;
        float w1 = v1 ? __int_as_float(e1.y) : 0.f;
        float w2 = v2 ? __int_as_float(e2.y) : 0.f;
        float w3 = v3 ? __int_as_float(e3.y) : 0.f;
        float4 g0 = *(const float4*)(h_cur + ((size_t)e0.x << 6) + fl);
        float4 g1 = *(const float4*)(h_cur + ((size_t)e1.x << 6) + fl);
        float4 g2 = *(const float4*)(h_cur + ((size_t)e2.x << 6) + fl);
        float4 g3 = *(const float4*)(h_cur + ((size_t)e3.x << 6) + fl);
        acc.x = fmaf(w0, g0.x, acc.x); acc.y = fmaf(w0, g0.y, acc.y);
        acc.z = fmaf(w0, g0.z, acc.z); acc.w = fmaf(w0, g0.w, acc.w);
        acc.x = fmaf(w1, g1.x, acc.x); acc.y = fmaf(w1, g1.y, acc.y);
        acc.z = fmaf(w1, g1.z, acc.z); acc.w = fmaf(w1, g1.w, acc.w);
        acc.x = fmaf(w2, g2.x, acc.x); acc.y = fmaf(w2, g2.y, acc.y);
        acc.z = fmaf(w2, g2.z, acc.z); acc.w = fmaf(w2, g2.w, acc.w);
        acc.x = fmaf(w3, g3.x, acc.x); acc.y = fmaf(w3, g3.y, acc.y);
        acc.z = fmaf(w3, g3.z, acc.z); acc.w = fmaf(w3, g3.w, acc.w);
    }
    for (; t < steps; ++t) {
        bool v0 = (t < deg);
        int2 e0 = edata[v0 ? (beg + t) : 0];
        float w0 = v0 ? __int_as_float(e0.y) : 0.f;
        float4 g0 = *(const float4*)(h_cur + ((size_t)e0.x << 6) + fl);
        acc.x = fmaf(w0, g0.x, acc.x); acc.y = fmaf(w0, g0.y, acc.y);
        acc.z = fmaf(w0, g0.z, acc.z); acc.w = fmaf(w0, g0.w, acc.w);
    }
    size_t o = ((size_t)node << 6) + fl;
    float4 hv = *(const float4*)(h0 + o);
    float4 r;
    const float s = 1.0f - ALPHA;
    r.x = fmaf(s, hv.x, acc.x); r.y = fmaf(s, hv.y, acc.y);
    r.z = fmaf(s, hv.z, acc.z); r.w = fmaf(s, hv.w, acc.w);
    *(float4*)(h_next + o) = r;
}

// out = h @ W_out + b_out. Thread per node; W_out (10 KB) in LDS.
__global__ __launch_bounds__(256) void linear_out_kernel(
        const float* __restrict__ h, const float* __restrict__ W,
        const float* __restrict__ b, float* __restrict__ out) {
    __shared__ float ws[NHID * NCLASSES];
    __shared__ float bs[NCLASSES];
    int tid = threadIdx.x;
    for (int i = tid; i < NHID * NCLASSES; i += 256) ws[i] = W[i];
    if (tid < NCLASSES) bs[tid] = b[tid];
    __syncthreads();
    int node = blockIdx.x * 256 + tid;
    if (node >= NNODES) return;
    float acc[NCLASSES];
#pragma unroll
    for (int c = 0; c < NCLASSES; ++c) acc[c] = bs[c];
    const float* hr = h + (size_t)node * NHID;
#pragma unroll
    for (int kq = 0; kq < NHID; kq += 16) {
        float hv[16];
        *(float4*)(hv)      = *(const float4*)(hr + kq);
        *(float4*)(hv + 4)  = *(const float4*)(hr + kq + 4);
        *(float4*)(hv + 8)  = *(const float4*)(hr + kq + 8);
        *(float4*)(hv + 12) = *(const float4*)(hr + kq + 12);
#pragma unroll
        for (int kk = 0; kk < 16; ++kk) {
#pragma unroll
            for (int c = 0; c < NCLASSES; ++c)
                acc[c] = fmaf(hv[kk], ws[(kq + kk) * NCLASSES + c], acc[c]);
        }
    }
#pragma unroll
    for (int c = 0; c < NCLASSES; ++c)
        out[(size_t)node * NCLASSES + c] = acc[c];
}

extern "C" void kernel_launch(void* const* d_in, const int* in_sizes, int n_in,
                              void* d_out, int out_size, void* d_ws, size_t ws_size,
                              hipStream_t stream) {
    const float* x     = (const float*)d_in[0];
    const int*   ei    = (const int*)d_in[1];
    const float* ew    = (const float*)d_in[2];
    const float* W_in  = (const float*)d_in[3];
    const float* b_in  = (const float*)d_in[4];
    const float* W_out = (const float*)d_in[5];
    const float* b_out = (const float*)d_in[6];
    float* out = (float*)d_out;

    const int HN = NNODES * NHID;
    float* h0 = (float*)d_ws;
    float* ha = h0 + HN;
    float* hb = ha + HN;
    int2*  edata   = (int2*)(hb + HN);
    int*   row_ptr = (int*)(edata + NEDGES);
    int*   cursor  = row_ptr + (NNODES + 1);
    int*   counts  = cursor + NNODES;
    int*   bsum    = counts + NNODES;
    int*   boff    = bsum + 64;

    const int* src = ei;
    const int* dst = ei + NEDGES;

    // ---- CSR build ----
    zero_counts_kernel<<<(NNODES + 255) / 256, 256, 0, stream>>>(counts);
    hist_kernel<<<(NEDGES + 255) / 256, 256, 0, stream>>>(dst, counts);
    const int NB = (NNODES + 1023) / 1024;
    scan1_kernel<<<NB, 1024, 0, stream>>>(counts, row_ptr, bsum);
    scan2_kernel<<<1, 64, 0, stream>>>(bsum, boff);
    scan3_kernel<<<(NNODES + 256) / 256, 256, 0, stream>>>(boff, row_ptr, cursor);
    csr_scatter_kernel<<<(NEDGES + 255) / 256, 256, 0, stream>>>(src, dst, ew, cursor, edata);

    // ---- h0 = x @ W_in + b_in ----
    linear_in_kernel<<<(NNODES + 63) / 64, 256, 0, stream>>>(x, W_in, b_in, h0);

    // ---- 10 APPNP layers ----
    float* cur = h0;
    float* nxt = ha;
    for (int l = 0; l < NLAYERS; ++l) {
        spmm_pull_kernel<<<(NNODES / 4 * 64) / 256, 256, 0, stream>>>(
            edata, row_ptr, cur, h0, nxt);
        cur = nxt;
        nxt = (cur == ha) ? hb : ha;
    }

    // ---- out = cur @ W_out + b_out ----
    linear_out_kernel<<<(NNODES + 255) / 256, 256, 0, stream>>>(cur, W_out, b_out, out);
}

// Round 6
// 375.502 us; speedup vs baseline: 1.4646x; 1.4646x over previous
//
#include <hip/hip_runtime.h>

#define NNODES 50000
#define NEDGES 800000
#define NFEAT 512
#define NHID 64
#define NCLASSES 40
#define NLAYERS 10
#define ALPHA 0.8f

typedef unsigned int uint32;
typedef unsigned short bf16_t;

__device__ __forceinline__ float bflo(uint32 u) { return __uint_as_float(u << 16); }
__device__ __forceinline__ float bfhi(uint32 u) { return __uint_as_float(u & 0xFFFF0000u); }
__device__ __forceinline__ bf16_t f2bf(float f) {
    uint32 u = __float_as_uint(f);
    u += 0x7FFFu + ((u >> 16) & 1u);      // round-to-nearest-even
    return (bf16_t)(u >> 16);
}

// ---------------- CSR build (once per call) ----------------

__global__ void zero_counts_kernel(int* __restrict__ counts) {
    int i = blockIdx.x * blockDim.x + threadIdx.x;
    if (i < NNODES) counts[i] = 0;
}

__global__ void hist_kernel(const int* __restrict__ dst, int* __restrict__ counts) {
    int e = blockIdx.x * blockDim.x + threadIdx.x;
    if (e >= NEDGES) return;
    atomicAdd(&counts[dst[e]], 1);
}

__global__ void scan1_kernel(const int* __restrict__ counts,
                             int* __restrict__ row_ptr,
                             int* __restrict__ bsum) {
    __shared__ int sd[1024];
    int tid = threadIdx.x;
    int i = blockIdx.x * 1024 + tid;
    int v = (i < NNODES) ? counts[i] : 0;
    sd[tid] = v;
    __syncthreads();
    for (int off = 1; off < 1024; off <<= 1) {
        int t = (tid >= off) ? sd[tid - off] : 0;
        __syncthreads();
        sd[tid] += t;
        __syncthreads();
    }
    if (i < NNODES) row_ptr[i] = sd[tid] - v;
    if (tid == 1023) bsum[blockIdx.x] = sd[1023];
}

__global__ void scan2_kernel(const int* __restrict__ bsum, int* __restrict__ boff) {
    int tid = threadIdx.x;
    const int NB = (NNODES + 1023) / 1024;   // 49
    int v0 = (tid < NB) ? bsum[tid] : 0;
    int v = v0;
#pragma unroll
    for (int off = 1; off < 64; off <<= 1) {
        int t = __shfl_up(v, off);
        if (tid >= off) v += t;
    }
    if (tid < NB) boff[tid] = v - v0;
    if (tid == NB - 1) boff[NB] = v;
}

__global__ void scan3_kernel(const int* __restrict__ boff,
                             int* __restrict__ row_ptr,
                             int* __restrict__ cursor) {
    int i = blockIdx.x * blockDim.x + threadIdx.x;
    if (i < NNODES) {
        int rp = row_ptr[i] + boff[i >> 10];
        row_ptr[i] = rp;
        cursor[i] = rp;
    } else if (i == NNODES) {
        row_ptr[NNODES] = boff[(NNODES + 1023) / 1024];
    }
}

__global__ void csr_scatter_kernel(const int* __restrict__ src,
                                   const int* __restrict__ dst,
                                   const float* __restrict__ ew,
                                   int* __restrict__ cursor,
                                   int2* __restrict__ edata) {
    int e = blockIdx.x * blockDim.x + threadIdx.x;
    if (e >= NEDGES) return;
    int d = dst[e];
    int pos = atomicAdd(&cursor[d], 1);
    int2 ed;
    ed.x = src[e];
    ed.y = __float_as_int(ALPHA * ew[e]);
    edata[pos] = ed;
}

// ---------------- dense kernels ----------------

// h0 = bf16(x @ W_in + b_in). Block: 256 nodes x 64 cols, 256 threads,
// thread tile 8x8, x transposed + W both in LDS, register prefetch of
// the next k-chunk (grid < 1 block/CU, so no TLP to hide HBM latency).
__global__ __launch_bounds__(256) void linear_in_kernel(
        const float* __restrict__ x, const float* __restrict__ W,
        const float* __restrict__ b, bf16_t* __restrict__ h0) {
    __shared__ float xs[32][260];   // [k][node] transposed
    __shared__ float ws[32][68];    // [k][col]
    int tid = threadIdx.x;
    int nb = blockIdx.x * 256;
    int cg = tid & 7;               // col group: cols cg*8..cg*8+7
    int ng = tid >> 3;              // node group: nodes ng*8..ng*8+7
    float acc[8][8];
#pragma unroll
    for (int i = 0; i < 8; ++i)
#pragma unroll
        for (int j = 0; j < 8; ++j) acc[i][j] = 0.f;

    float4 xv[8];
    float4 wv[2];

#define LOAD_CHUNK(kc)                                                       \
    {                                                                        \
        _Pragma("unroll")                                                    \
        for (int q = 0; q < 8; ++q) {                                        \
            int li = tid + q * 256;                                          \
            int r = li >> 3, f4 = li & 7;                                    \
            int row = nb + r;                                                \
            xv[q] = make_float4(0.f, 0.f, 0.f, 0.f);                         \
            if (row < NNODES)                                                \
                xv[q] = *(const float4*)(x + (size_t)row * NFEAT + (kc) + f4 * 4); \
        }                                                                    \
        _Pragma("unroll")                                                    \
        for (int q = 0; q < 2; ++q) {                                        \
            int li = tid + q * 256;                                          \
            int k = li >> 4, j4 = li & 15;                                   \
            wv[q] = *(const float4*)(W + (size_t)((kc) + k) * NHID + j4 * 4);\
        }                                                                    \
    }

#define STORE_CHUNK()                                                        \
    {                                                                        \
        _Pragma("unroll")                                                    \
        for (int q = 0; q < 8; ++q) {                                        \
            int li = tid + q * 256;                                          \
            int r = li >> 3, f4 = li & 7;                                    \
            xs[f4 * 4 + 0][r] = xv[q].x;                                     \
            xs[f4 * 4 + 1][r] = xv[q].y;                                     \
            xs[f4 * 4 + 2][r] = xv[q].z;                                     \
            xs[f4 * 4 + 3][r] = xv[q].w;                                     \
        }                                                                    \
        _Pragma("unroll")                                                    \
        for (int q = 0; q < 2; ++q) {                                        \
            int li = tid + q * 256;                                          \
            int k = li >> 4, j4 = li & 15;                                   \
            *(float4*)(&ws[k][j4 * 4]) = wv[q];                              \
        }                                                                    \
    }

    LOAD_CHUNK(0);
    STORE_CHUNK();
    __syncthreads();
    for (int kc = 0; kc < NFEAT; kc += 32) {
        if (kc + 32 < NFEAT) LOAD_CHUNK(kc + 32);   // prefetch into regs
#pragma unroll 4
        for (int k = 0; k < 32; ++k) {
            float a[8], w[8];
            *(float4*)(a)     = *(const float4*)(&xs[k][ng * 8]);
            *(float4*)(a + 4) = *(const float4*)(&xs[k][ng * 8 + 4]);
            *(float4*)(w)     = *(const float4*)(&ws[k][cg * 8]);
            *(float4*)(w + 4) = *(const float4*)(&ws[k][cg * 8 + 4]);
#pragma unroll
            for (int i = 0; i < 8; ++i)
#pragma unroll
                for (int j = 0; j < 8; ++j)
                    acc[i][j] = fmaf(a[i], w[j], acc[i][j]);
        }
        __syncthreads();
        if (kc + 32 < NFEAT) {
            STORE_CHUNK();
            __syncthreads();
        }
    }
    float bb[8];
    *(float4*)(bb)     = *(const float4*)(b + cg * 8);
    *(float4*)(bb + 4) = *(const float4*)(b + cg * 8 + 4);
#pragma unroll
    for (int i = 0; i < 8; ++i) {
        int n = nb + ng * 8 + i;
        if (n < NNODES) {
            uint4 o;
            o.x = (uint32)f2bf(acc[i][0] + bb[0]) | ((uint32)f2bf(acc[i][1] + bb[1]) << 16);
            o.y = (uint32)f2bf(acc[i][2] + bb[2]) | ((uint32)f2bf(acc[i][3] + bb[3]) << 16);
            o.z = (uint32)f2bf(acc[i][4] + bb[4]) | ((uint32)f2bf(acc[i][5] + bb[5]) << 16);
            o.w = (uint32)f2bf(acc[i][6] + bb[6]) | ((uint32)f2bf(acc[i][7] + bb[7]) << 16);
            *(uint4*)(h0 + (size_t)n * NHID + cg * 8) = o;
        }
    }
#undef LOAD_CHUNK
#undef STORE_CHUNK
}

// accumulate one bf16x8 gather scaled by w into acc[8]
__device__ __forceinline__ void acc_edge(float* acc, uint4 g, float wgt) {
    acc[0] = fmaf(wgt, bflo(g.x), acc[0]);
    acc[1] = fmaf(wgt, bfhi(g.x), acc[1]);
    acc[2] = fmaf(wgt, bflo(g.y), acc[2]);
    acc[3] = fmaf(wgt, bfhi(g.y), acc[3]);
    acc[4] = fmaf(wgt, bflo(g.z), acc[4]);
    acc[5] = fmaf(wgt, bfhi(g.z), acc[5]);
    acc[6] = fmaf(wgt, bflo(g.w), acc[6]);
    acc[7] = fmaf(wgt, bfhi(g.w), acc[7]);
}

// pull SpMM on bf16 h: 8 nodes/wave, 8 lanes x uint4 (8 bf16 feats) per node,
// fp32 accumulation, 2 edges in flight.
__global__ __launch_bounds__(256) void spmm_pull_kernel(
        const int2* __restrict__ edata, const int* __restrict__ row_ptr,
        const bf16_t* __restrict__ h_cur, const bf16_t* __restrict__ h0,
        bf16_t* __restrict__ h_next) {
    int gid = blockIdx.x * blockDim.x + threadIdx.x;
    int wave = gid >> 6;
    int lane = threadIdx.x & 63;
    int grp = lane >> 3;            // 0..7
    int fl = (lane & 7) << 3;       // feature base (8 bf16 = 16 B)
    int node = wave * 8 + grp;
    int beg = 0, deg = 0;
    if (node < NNODES) {
        beg = row_ptr[node];
        deg = row_ptr[node + 1] - beg;
    }
    int steps = deg;
    steps = max(steps, __shfl_xor(steps, 8));
    steps = max(steps, __shfl_xor(steps, 16));
    steps = max(steps, __shfl_xor(steps, 32));

    float acc[8];
#pragma unroll
    for (int j = 0; j < 8; ++j) acc[j] = 0.f;

    int t = 0;
    for (; t + 1 < steps; t += 2) {
        bool v0 = (t < deg), v1 = (t + 1 < deg);
        int2 e0 = edata[v0 ? (beg + t) : 0];
        int2 e1 = edata[v1 ? (beg + t + 1) : 0];
        float w0 = v0 ? __int_as_float(e0.y) : 0.f;
        float w1 = v1 ? __int_as_float(e1.y) : 0.f;
        uint4 g0 = *(const uint4*)(h_cur + ((size_t)e0.x << 6) + fl);
        uint4 g1 = *(const uint4*)(h_cur + ((size_t)e1.x << 6) + fl);
        acc_edge(acc, g0, w0);
        acc_edge(acc, g1, w1);
    }
    if (t < steps) {
        bool v0 = (t < deg);
        int2 e0 = edata[v0 ? (beg + t) : 0];
        float w0 = v0 ? __int_as_float(e0.y) : 0.f;
        uint4 g0 = *(const uint4*)(h_cur + ((size_t)e0.x << 6) + fl);
        acc_edge(acc, g0, w0);
    }

    if (node < NNODES) {
        size_t o = ((size_t)node << 6) + fl;
        uint4 hv = *(const uint4*)(h0 + o);
        const float s = 1.0f - ALPHA;
        float r[8];
        r[0] = fmaf(s, bflo(hv.x), acc[0]);
        r[1] = fmaf(s, bfhi(hv.x), acc[1]);
        r[2] = fmaf(s, bflo(hv.y), acc[2]);
        r[3] = fmaf(s, bfhi(hv.y), acc[3]);
        r[4] = fmaf(s, bflo(hv.z), acc[4]);
        r[5] = fmaf(s, bfhi(hv.z), acc[5]);
        r[6] = fmaf(s, bflo(hv.w), acc[6]);
        r[7] = fmaf(s, bfhi(hv.w), acc[7]);
        uint4 ov;
        ov.x = (uint32)f2bf(r[0]) | ((uint32)f2bf(r[1]) << 16);
        ov.y = (uint32)f2bf(r[2]) | ((uint32)f2bf(r[3]) << 16);
        ov.z = (uint32)f2bf(r[4]) | ((uint32)f2bf(r[5]) << 16);
        ov.w = (uint32)f2bf(r[6]) | ((uint32)f2bf(r[7]) << 16);
        *(uint4*)(h_next + o) = ov;
    }
}

// out = bf16h @ W_out + b_out. Thread per node; W_out (10 KB) in LDS.
__global__ __launch_bounds__(256) void linear_out_kernel(
        const bf16_t* __restrict__ h, const float* __restrict__ W,
        const float* __restrict__ b, float* __restrict__ out) {
    __shared__ float wsh[NHID * NCLASSES];
    __shared__ float bs[NCLASSES];
    int tid = threadIdx.x;
    for (int i = tid; i < NHID * NCLASSES; i += 256) wsh[i] = W[i];
    if (tid < NCLASSES) bs[tid] = b[tid];
    __syncthreads();
    int node = blockIdx.x * 256 + tid;
    if (node >= NNODES) return;
    float acc[NCLASSES];
#pragma unroll
    for (int c = 0; c < NCLASSES; ++c) acc[c] = bs[c];
    const bf16_t* hr = h + (size_t)node * NHID;
#pragma unroll
    for (int q = 0; q < 8; ++q) {
        uint4 v = *(const uint4*)(hr + q * 8);
        float hv[8];
        hv[0] = bflo(v.x); hv[1] = bfhi(v.x);
        hv[2] = bflo(v.y); hv[3] = bfhi(v.y);
        hv[4] = bflo(v.z); hv[5] = bfhi(v.z);
        hv[6] = bflo(v.w); hv[7] = bfhi(v.w);
#pragma unroll
        for (int kk = 0; kk < 8; ++kk) {
#pragma unroll
            for (int c = 0; c < NCLASSES; ++c)
                acc[c] = fmaf(hv[kk], wsh[(q * 8 + kk) * NCLASSES + c], acc[c]);
        }
    }
    float* op = out + (size_t)node * NCLASSES;
#pragma unroll
    for (int c = 0; c < NCLASSES; c += 4)
        *(float4*)(op + c) = make_float4(acc[c], acc[c + 1], acc[c + 2], acc[c + 3]);
}

extern "C" void kernel_launch(void* const* d_in, const int* in_sizes, int n_in,
                              void* d_out, int out_size, void* d_ws, size_t ws_size,
                              hipStream_t stream) {
    const float* x     = (const float*)d_in[0];
    const int*   ei    = (const int*)d_in[1];
    const float* ew    = (const float*)d_in[2];
    const float* W_in  = (const float*)d_in[3];
    const float* b_in  = (const float*)d_in[4];
    const float* W_out = (const float*)d_in[5];
    const float* b_out = (const float*)d_in[6];
    float* out = (float*)d_out;

    const int HN = NNODES * NHID;            // 3.2M elements
    bf16_t* h0 = (bf16_t*)d_ws;              // 6.4 MB each
    bf16_t* ha = h0 + HN;
    bf16_t* hb = ha + HN;
    int2* edata   = (int2*)(hb + HN);        // 6.4 MB, 8B-aligned
    int*  row_ptr = (int*)(edata + NEDGES);
    int*  cursor  = row_ptr + (NNODES + 1);
    int*  counts  = cursor + NNODES;
    int*  bsum    = counts + NNODES;
    int*  boff    = bsum + 64;

    const int* src = ei;
    const int* dst = ei + NEDGES;

    // ---- CSR build ----
    zero_counts_kernel<<<(NNODES + 255) / 256, 256, 0, stream>>>(counts);
    hist_kernel<<<(NEDGES + 255) / 256, 256, 0, stream>>>(dst, counts);
    const int NB = (NNODES + 1023) / 1024;
    scan1_kernel<<<NB, 1024, 0, stream>>>(counts, row_ptr, bsum);
    scan2_kernel<<<1, 64, 0, stream>>>(bsum, boff);
    scan3_kernel<<<(NNODES + 256) / 256, 256, 0, stream>>>(boff, row_ptr, cursor);
    csr_scatter_kernel<<<(NEDGES + 255) / 256, 256, 0, stream>>>(src, dst, ew, cursor, edata);

    // ---- h0 = bf16(x @ W_in + b_in) ----
    linear_in_kernel<<<(NNODES + 255) / 256, 256, 0, stream>>>(x, W_in, b_in, h0);

    // ---- 10 APPNP layers ----
    const int NWAVES = (NNODES + 7) / 8;                 // 6250
    const int SPMM_BLOCKS = (NWAVES * 64 + 255) / 256;   // 1563
    bf16_t* cur = h0;
    bf16_t* nxt = ha;
    for (int l = 0; l < NLAYERS; ++l) {
        spmm_pull_kernel<<<SPMM_BLOCKS, 256, 0, stream>>>(edata, row_ptr, cur, h0, nxt);
        cur = nxt;
        nxt = (cur == ha) ? hb : ha;
    }

    // ---- out = cur @ W_out + b_out ----
    linear_out_kernel<<<(NNODES + 255) / 256, 256, 0, stream>>>(cur, W_out, b_out, out);
}